// Round 1
// baseline (4209.582 us; speedup 1.0000x reference)
//
#include <hip/hip_runtime.h>
#include <math.h>

#define T_   2048
#define DIN  512
#define H_   384
#define H4_  1536
#define BT_  16384

typedef _Float16 half_t;
typedef _Float16 f16x8 __attribute__((ext_vector_type(8)));
typedef float f32x4 __attribute__((ext_vector_type(4)));

#define LO_SCALE 2048.0f
#define LO_INV   4.8828125e-4f

// lgkm-only barrier: prefetched global->VGPR loads stay in flight across it.
__device__ __forceinline__ void lds_barrier() {
    asm volatile("s_waitcnt lgkmcnt(0)\n\ts_barrier" ::: "memory");
}

__device__ __forceinline__ void split2(float v, half_t* hi, half_t* lo) {
    half_t h = (half_t)v;
    *hi = h;
    *lo = (half_t)((v - (float)h) * LO_SCALE);
}

// ---------------------------------------------------------------------------
// fp32 -> (hi, lo*2048) fp16 element-wise split
// ---------------------------------------------------------------------------
__global__ void k_split(const float* __restrict__ in, half_t* __restrict__ hi,
                        half_t* __restrict__ lo, long n) {
    long i = (long)blockIdx.x * 256 + threadIdx.x;
    if (i >= n) return;
    split2(in[i], hi + i, lo + i);
}

// enc_w [H][DIN][7] -> [H][tap*512+i] hi/lo
__global__ void k_split_encw(const float* __restrict__ in, half_t* __restrict__ hi,
                             half_t* __restrict__ lo) {
    int idx = blockIdx.x * 256 + threadIdx.x;
    if (idx >= H_ * 3584) return;
    int n = idx / 3584;
    int r = idx % 3584;
    int tap = r >> 9, i = r & 511;
    split2(in[n * 3584 + i * 7 + tap], hi + idx, lo + idx);
}

// ---------------------------------------------------------------------------
// Row-wise LayerNorm over H=384 (fp32 in/out, in-place safe), one wave per row
// ---------------------------------------------------------------------------
__global__ void k_ln(const float* __restrict__ in, float* __restrict__ out,
                     const float* __restrict__ g, const float* __restrict__ b) {
    int row = blockIdx.x;
    int lane = threadIdx.x;
    const float* ir = in + (long)row * H_;
    float v[6];
    float s = 0.f;
#pragma unroll
    for (int j = 0; j < 6; ++j) { v[j] = ir[lane + (j << 6)]; s += v[j]; }
#pragma unroll
    for (int o = 32; o > 0; o >>= 1) s += __shfl_down(s, o, 64);
    s = __shfl(s, 0, 64);
    float mean = s * (1.f / 384.f);
    float q = 0.f;
#pragma unroll
    for (int j = 0; j < 6; ++j) { float d = v[j] - mean; q += d * d; }
#pragma unroll
    for (int o = 32; o > 0; o >>= 1) q += __shfl_down(q, o, 64);
    q = __shfl(q, 0, 64);
    float rstd = rsqrtf(q * (1.f / 384.f) + 1e-5f);
    float* orow = out + (long)row * H_;
#pragma unroll
    for (int j = 0; j < 6; ++j) {
        int c = lane + (j << 6);
        orow[c] = (v[j] - mean) * rstd * g[c] + b[c];
    }
}

// ---------------------------------------------------------------------------
// Fused depthwise conv (k=7, pad=3) + LayerNorm; emits fp16 hi/lo for GEMM1
// 4 rows per block (one per wave) so the 7-tap t-overlap is L1-resident.
// ---------------------------------------------------------------------------
__global__ __launch_bounds__(256) void k_dwconv_ln(
    const float* __restrict__ h, half_t* __restrict__ oh,
    half_t* __restrict__ ol,
    const float* __restrict__ w, const float* __restrict__ wb,
    const float* __restrict__ g, const float* __restrict__ gb) {
    int row = (blockIdx.x << 2) + (threadIdx.x >> 6);
    int b = row >> 11;
    int t = row & 2047;
    int lane = threadIdx.x & 63;
    const float* hb = h + ((long)b * T_) * H_;
    float v[6];
    float s = 0.f;
#pragma unroll
    for (int j = 0; j < 6; ++j) {
        int c = lane + (j << 6);
        float acc = wb[c];
        const float* wc = w + c * 7;
#pragma unroll
        for (int k = 0; k < 7; ++k) {
            int tt = t + k - 3;
            if ((unsigned)tt < (unsigned)T_)
                acc = fmaf(hb[(long)tt * H_ + c], wc[k], acc);
        }
        v[j] = acc;
        s += acc;
    }
#pragma unroll
    for (int o = 32; o > 0; o >>= 1) s += __shfl_down(s, o, 64);
    s = __shfl(s, 0, 64);
    float mean = s * (1.f / 384.f);
    float q = 0.f;
#pragma unroll
    for (int j = 0; j < 6; ++j) { float d = v[j] - mean; q += d * d; }
#pragma unroll
    for (int o = 32; o > 0; o >>= 1) q += __shfl_down(q, o, 64);
    q = __shfl(q, 0, 64);
    float rstd = rsqrtf(q * (1.f / 384.f) + 1e-5f);
    long ro = (long)row * H_;
#pragma unroll
    for (int j = 0; j < 6; ++j) {
        int c = lane + (j << 6);
        float val = (v[j] - mean) * rstd * g[c] + gb[c];
        split2(val, oh + ro + c, ol + ro + c);
    }
}

// ---------------------------------------------------------------------------
// MFMA fp16x3 GEMM, BM=64 x BN=128, BK=32, 256 threads = 4 waves of 64x32
// wave tile (4x2 frags 16x16x32, wm=0, wn=wid*32). 48 KB LDS -> 3 blocks/CU.
// Swizzle: granule position p = (g ^ (row>>1)) & 3  -> every quarter-wave
// (fixed quad) hits all 8 16B bank slots exactly twice, read AND store side
// (old (g ^ row)&3 left a 4-way conflict: 1.65e7 conflict cycles/dispatch).
// 2-deep global prefetch: two named register sets (static indexing), loads
// issued 2 K-steps before their ds_write -> vmcnt wait covered by 2 iters of
// MFMA. Single lgkm-only barrier per K-step. nIter must be EVEN (all K are
// multiples of 64: 3584, 384, 1536).
// MODE 0: A = x im2row (K=3584), +bias, fp32 out
// MODE 1: +bias, exact GELU, fp16 hi/lo out (smem round-trip for coalescing)
// MODE 2: +bias, +res, fp32 out
// LDS halves layout: Ah buf*2048 | Al 4096+buf*2048 | Bh 8192+buf*4096
//                    | Bl 16384+buf*4096   (total 24576 halves = 48 KB)
// ---------------------------------------------------------------------------
template <int MODE>
__global__ __launch_bounds__(256, 3) void k_mgemm64(
    const half_t* __restrict__ Ah, const half_t* __restrict__ Al,
    const half_t* __restrict__ Bh, const half_t* __restrict__ Bl,
    const float* __restrict__ bias, const float* __restrict__ res,
    float* __restrict__ Cf, half_t* __restrict__ Ch, half_t* __restrict__ Cl,
    int N, int K) {
    __shared__ __align__(16) half_t smem[24576];
    const int tid = threadIdx.x;
    const int lane = tid & 63, wid = tid >> 6;
    const int wn = wid << 5;
    const int quad = lane >> 4, l16 = lane & 15;
    const int m0 = blockIdx.x << 6, n0 = blockIdx.y << 7;
    const int ar = tid >> 2;          // staging row 0..63
    const int ak = (tid & 3) << 3;    // k offset (halves), granule = tid&3

    long aoff = 0;
    int tt0 = 0, bq = 0;
    if (MODE == 0) {
        bq = m0 >> 11;
        tt0 = (m0 & 2047) + ar - 3;
    } else {
        aoff = (long)(m0 + ar) * K + ak;
    }
    const long boff0 = (long)(n0 + ar) * K + ak;
    const long boff1 = boff0 + (long)64 * K;

    struct R6 { float4 ah, al, bh0, bl0, bh1, bl1; };
    R6 r0, r1;
    auto loadregs = [&](R6& r, int k0) {
        if (MODE == 0) {
            int kk = k0 + ak;
            int tap = kk >> 9, ii = kk & 511;
            int ta = tt0 + tap;
            r.ah = r.al = make_float4(0.f, 0.f, 0.f, 0.f);
            if ((unsigned)ta < 2048u) {
                long o = ((long)bq * 2048 + ta) * 512 + ii;
                r.ah = *(const float4*)(Ah + o);
                r.al = *(const float4*)(Al + o);
            }
        } else {
            r.ah = *(const float4*)(Ah + aoff + k0);
            r.al = *(const float4*)(Al + aoff + k0);
        }
        r.bh0 = *(const float4*)(Bh + boff0 + k0);
        r.bl0 = *(const float4*)(Bl + boff0 + k0);
        r.bh1 = *(const float4*)(Bh + boff1 + k0);
        r.bl1 = *(const float4*)(Bl + boff1 + k0);
    };
    // swizzled staging position: granule g stored at (g ^ (row>>1)) & 3
    const int aw = ar * 32 + ((((tid & 3) ^ (ar >> 1)) & 3) << 3);
    auto storebuf = [&](const R6& r, int buf) {
        *(float4*)&smem[buf * 2048 + aw] = r.ah;
        *(float4*)&smem[4096 + buf * 2048 + aw] = r.al;
        int b = 8192 + buf * 4096 + aw;
        *(float4*)&smem[b] = r.bh0;
        *(float4*)&smem[b + 2048] = r.bh1;
        *(float4*)&smem[b + 8192] = r.bl0;
        *(float4*)&smem[b + 8192 + 2048] = r.bl1;
    };

    f32x4 acc1[4][2] = {};
    f32x4 acc2[4][2] = {};
    // read-side swizzle: position (quad ^ (row>>1))&3 recovers granule quad
    // for every fragment row (16f+l16, wn+16g+l16: (row>>1)&3 == (l16>>1)&3)
    const int sw = ((quad ^ (l16 >> 1)) & 3) << 3;

    auto compute = [&](int buf) {
        const int ab = buf * 2048 + l16 * 32 + sw;
        const int bb = 8192 + buf * 4096 + (wn + l16) * 32 + sw;
        f16x8 fah[4], fal[4], fgh[2], fgl[2];
#pragma unroll
        for (int f = 0; f < 4; ++f) {
            fah[f] = *(const f16x8*)&smem[ab + f * 512];
            fal[f] = *(const f16x8*)&smem[ab + 4096 + f * 512];
        }
#pragma unroll
        for (int g = 0; g < 2; ++g) {
            fgh[g] = *(const f16x8*)&smem[bb + g * 512];
            fgl[g] = *(const f16x8*)&smem[bb + 8192 + g * 512];
        }
#pragma unroll
        for (int f = 0; f < 4; ++f)
#pragma unroll
            for (int g = 0; g < 2; ++g)
                acc2[f][g] = __builtin_amdgcn_mfma_f32_16x16x32_f16(fah[f], fgl[g], acc2[f][g], 0, 0, 0);
#pragma unroll
        for (int f = 0; f < 4; ++f)
#pragma unroll
            for (int g = 0; g < 2; ++g)
                acc2[f][g] = __builtin_amdgcn_mfma_f32_16x16x32_f16(fal[f], fgh[g], acc2[f][g], 0, 0, 0);
#pragma unroll
        for (int f = 0; f < 4; ++f)
#pragma unroll
            for (int g = 0; g < 2; ++g)
                acc1[f][g] = __builtin_amdgcn_mfma_f32_16x16x32_f16(fah[f], fgh[g], acc1[f][g], 0, 0, 0);
    };

    const int nIter = K >> 5;
    // prologue: r0 <- tile0, r1 <- tile1, stage tile0, r0 <- tile2
    loadregs(r0, 0);
    loadregs(r1, 32);
    storebuf(r0, 0);
    if (nIter > 2) loadregs(r0, 64);
    // steady state (even it): buf0 holds tile it, r1 holds tile it+1 (stored
    // now), r0 holds tile it+2 (in flight); reload stored set <- tile it+3.
    for (int it = 0; it < nIter; it += 2) {
        lds_barrier();
        compute(0);
        storebuf(r1, 1);
        if (it + 3 < nIter) loadregs(r1, (it + 3) << 5);
        lds_barrier();
        compute(1);
        if (it + 2 < nIter) {
            storebuf(r0, 0);
            if (it + 4 < nIter) loadregs(r0, (it + 4) << 5);
        }
    }

    float bv[2];
    bv[0] = bias[n0 + wn + l16];
    bv[1] = bias[n0 + wn + 16 + l16];

    if (MODE == 1) {
        // GELU + fp16 hi/lo split, smem round-trip for coalesced stores.
        // Planes: hi @0, lo @8704, row stride 136 halves (272 B: spreads rows
        // across banks, 16B-aligned for the float4 copy-out).
        __syncthreads();
#pragma unroll
        for (int f = 0; f < 4; ++f)
#pragma unroll
            for (int g = 0; g < 2; ++g)
#pragma unroll
                for (int r = 0; r < 4; ++r) {
                    int rm = f * 16 + quad * 4 + r;
                    int cn = wn + g * 16 + l16;
                    float v = acc1[f][g][r] + acc2[f][g][r] * LO_INV + bv[g];
                    v = 0.5f * v * (1.0f + erff(v * 0.70710678118654752f));
                    half_t hh = (half_t)v;
                    smem[rm * 136 + cn] = hh;
                    smem[8704 + rm * 136 + cn] = (half_t)((v - (float)hh) * LO_SCALE);
                }
        __syncthreads();
        int row = tid >> 2, c0 = (tid & 3) << 5;
        long go = (long)(m0 + row) * N + n0 + c0;
        int so = row * 136 + c0;
#pragma unroll
        for (int u = 0; u < 4; ++u) {
            *(float4*)(Ch + go + u * 8) = *(const float4*)&smem[so + u * 8];
            *(float4*)(Cl + go + u * 8) = *(const float4*)&smem[8704 + so + u * 8];
        }
    } else {
#pragma unroll
        for (int f = 0; f < 4; ++f)
#pragma unroll
            for (int g = 0; g < 2; ++g)
#pragma unroll
                for (int r = 0; r < 4; ++r) {
                    long row = m0 + f * 16 + quad * 4 + r;
                    int col = n0 + wn + g * 16 + l16;
                    float v = acc1[f][g][r] + acc2[f][g][r] * LO_INV + bv[g];
                    long o = row * N + col;
                    if (MODE == 2) v += res[o];
                    Cf[o] = v;
                }
    }
}

// ---------------------------------------------------------------------------
// Fused out-conv (pointwise, C=8) + nearest-embedding argmin over K=8192
// ---------------------------------------------------------------------------
__global__ __launch_bounds__(256) void k_outconv_argmin(
    const float* __restrict__ h, const float* __restrict__ ow,
    const float* __restrict__ ob, const float* __restrict__ emb,
    int* __restrict__ outIdx) {
    __shared__ float hs[16][H_ + 1];
    __shared__ float zs[16][8];
    __shared__ float es[16 * 516];
    __shared__ float rb[16][16];
    __shared__ int ri[16][16];
    const int tid = threadIdx.x;
    const int row0 = blockIdx.x << 4;

    for (int i = tid; i < 16 * (H_ / 4); i += 256) {
        int r = i / 96;
        int c4 = (i % 96) << 2;
        float4 v = *(const float4*)&h[((long)(row0 + r)) * H_ + c4];
        hs[r][c4] = v.x; hs[r][c4 + 1] = v.y; hs[r][c4 + 2] = v.z; hs[r][c4 + 3] = v.w;
    }
    __syncthreads();

    if (tid < 128) {
        int r = tid & 15, c = tid >> 4;
        float acc = ob[c];
        const float* wc = ow + c * H_;
        for (int j = 0; j < H_; ++j) acc = fmaf(hs[r][j], wc[j], acc);
        zs[r][c] = acc;
    }
    __syncthreads();

    const int r = tid & 15;
    const int sl = tid >> 4;
    float z0 = zs[r][0], z1 = zs[r][1], z2 = zs[r][2], z3 = zs[r][3];
    float z4 = zs[r][4], z5 = zs[r][5], z6 = zs[r][6], z7 = zs[r][7];
    float best = 3.4e38f;
    int bi = 0;

    for (int ch = 0; ch < 8; ++ch) {
        __syncthreads();
        for (int i = tid; i < 2048; i += 256) {
            int e = i >> 1;
            int half = (i & 1) << 2;
            float4 src = *(const float4*)&emb[(((long)(ch << 10)) + e) * 8 + half];
            *(float4*)&es[(e >> 6) * 516 + ((e & 63) << 3) + half] = src;
        }
        __syncthreads();
        const float* ep = es + sl * 516;
        int gbase = (ch << 10) + (sl << 6);
#pragma unroll 4
        for (int j = 0; j < 64; ++j) {
            float4 e0 = *(const float4*)(ep + (j << 3));
            float4 e1 = *(const float4*)(ep + (j << 3) + 4);
            float t, d;
            t = e0.x - z0; d = t * t;
            t = e0.y - z1; d = fmaf(t, t, d);
            t = e0.z - z2; d = fmaf(t, t, d);
            t = e0.w - z3; d = fmaf(t, t, d);
            t = e1.x - z4; d = fmaf(t, t, d);
            t = e1.y - z5; d = fmaf(t, t, d);
            t = e1.z - z6; d = fmaf(t, t, d);
            t = e1.w - z7; d = fmaf(t, t, d);
            if (d < best) { best = d; bi = gbase + j; }
        }
    }
    rb[r][sl] = best;
    ri[r][sl] = bi;
    __syncthreads();
    if (sl == 0) {
        float bb = rb[r][0];
        int bbi = ri[r][0];
#pragma unroll
        for (int s2 = 1; s2 < 16; ++s2) {
            float v = rb[r][s2];
            int i2 = ri[r][s2];
            if (v < bb || (v == bb && i2 < bbi)) { bb = v; bbi = i2; }
        }
        outIdx[row0 + r] = bbi;
    }
}

// ---------------------------------------------------------------------------
// host launcher
// ---------------------------------------------------------------------------
extern "C" void kernel_launch(void* const* d_in, const int* in_sizes, int n_in,
                              void* d_out, int out_size, void* d_ws, size_t ws_size,
                              hipStream_t stream) {
    const float* x        = (const float*)d_in[0];
    const float* enc_w    = (const float*)d_in[1];
    const float* enc_b    = (const float*)d_in[2];
    const float* enc_ln_g = (const float*)d_in[3];
    const float* enc_ln_b = (const float*)d_in[4];
    const float* blk_dw_w = (const float*)d_in[5];
    const float* blk_dw_b = (const float*)d_in[6];
    const float* blk_ln_g = (const float*)d_in[7];
    const float* blk_ln_b = (const float*)d_in[8];
    const float* blk_w1   = (const float*)d_in[9];
    const float* blk_b1   = (const float*)d_in[10];
    const float* blk_w2   = (const float*)d_in[11];
    const float* blk_b2   = (const float*)d_in[12];
    const float* out_w    = (const float*)d_in[13];
    const float* out_b    = (const float*)d_in[14];
    const float* emb      = (const float*)d_in[15];
    int* out = (int*)d_out;

    char* base = (char*)d_ws;
    float*  h    = (float*)base;                       // 25165824 B
    half_t* tmph = (half_t*)(base + 25165824);         // 12582912 B
    half_t* tmpl = (half_t*)(base + 37748736);         // 12582912 B
    half_t* ht4h = (half_t*)(base + 50331648);         // 50331648 B
    half_t* ht4l = (half_t*)(base + 100663296);        // 50331648 B
    half_t* ench = (half_t*)(base + 150994944);        // 2752512 B
    half_t* encl = (half_t*)(base + 153747456);        // 2752512 B
    half_t* w1h  = (half_t*)(base + 156499968);        // 7077888 B
    half_t* w1l  = (half_t*)(base + 163577856);        // 7077888 B
    half_t* w2h  = (half_t*)(base + 170655744);        // 7077888 B
    half_t* w2l  = (half_t*)(base + 177733632);        // 7077888 B
    // x hi/lo alias the ht4 region (dead until first GEMM1)
    half_t* xh = ht4h;                                  // 16777216 B
    half_t* xl = (half_t*)(base + 50331648 + 16777216); // 16777216 B

    k_split<<<(8388608 + 255) / 256, 256, 0, stream>>>(x, xh, xl, 8388608L);
    k_split<<<(3538944 + 255) / 256, 256, 0, stream>>>(blk_w1, w1h, w1l, 3538944L);
    k_split<<<(3538944 + 255) / 256, 256, 0, stream>>>(blk_w2, w2h, w2l, 3538944L);
    k_split_encw<<<(H_ * 3584 + 255) / 256, 256, 0, stream>>>(enc_w, ench, encl);

    // encoder conv (im2row MFMA GEMM) -> h, then in-place LN
    k_mgemm64<0><<<dim3(256, 3), 256, 0, stream>>>(xh, xl, ench, encl, enc_b,
                                                   nullptr, h, nullptr, nullptr,
                                                   H_, 3584);
    k_ln<<<BT_, 64, 0, stream>>>(h, h, enc_ln_g, enc_ln_b);

    for (int i = 0; i < 6; ++i) {
        k_dwconv_ln<<<BT_ / 4, 256, 0, stream>>>(h, tmph, tmpl, blk_dw_w + i * H_ * 7,
                                                 blk_dw_b + i * H_, blk_ln_g + i * H_,
                                                 blk_ln_b + i * H_);
        // GEMM1 as 64x128-tile MODE 1: 3072 blocks = exactly 4 rounds at
        // 3 blocks/CU (vs old 512-thread kernel stuck at 1 block/CU on VGPRs)
        k_mgemm64<1><<<dim3(256, 12), 256, 0, stream>>>(
            tmph, tmpl, w1h + (long)i * 589824, w1l + (long)i * 589824,
            blk_b1 + i * H4_, nullptr, nullptr, ht4h, ht4l, H4_, H_);
        k_mgemm64<2><<<dim3(256, 3), 256, 0, stream>>>(
            ht4h, ht4l, w2h + (long)i * 589824, w2l + (long)i * 589824,
            blk_b2 + i * H_, h, h, nullptr, nullptr, H_, H4_);
    }

    k_outconv_argmin<<<BT_ / 16, 256, 0, stream>>>(h, out_w, out_b, emb, out);
}

// Round 2
// 1701.411 us; speedup vs baseline: 2.4742x; 2.4742x over previous
//
#include <hip/hip_runtime.h>
#include <math.h>

#define T_   2048
#define DIN  512
#define H_   384
#define H4_  1536
#define BT_  16384

typedef _Float16 half_t;
typedef _Float16 f16x8 __attribute__((ext_vector_type(8)));
typedef float f32x4 __attribute__((ext_vector_type(4)));

#define LO_SCALE 2048.0f
#define LO_INV   4.8828125e-4f

// lgkm-only barrier: prefetched global->VGPR loads stay in flight across it.
__device__ __forceinline__ void lds_barrier() {
    asm volatile("s_waitcnt lgkmcnt(0)\n\ts_barrier" ::: "memory");
}

__device__ __forceinline__ void split2(float v, half_t* hi, half_t* lo) {
    half_t h = (half_t)v;
    *hi = h;
    *lo = (half_t)((v - (float)h) * LO_SCALE);
}

// ---------------------------------------------------------------------------
// fp32 -> (hi, lo*2048) fp16 element-wise split
// ---------------------------------------------------------------------------
__global__ void k_split(const float* __restrict__ in, half_t* __restrict__ hi,
                        half_t* __restrict__ lo, long n) {
    long i = (long)blockIdx.x * 256 + threadIdx.x;
    if (i >= n) return;
    split2(in[i], hi + i, lo + i);
}

// enc_w [H][DIN][7] -> [H][tap*512+i] hi/lo
__global__ void k_split_encw(const float* __restrict__ in, half_t* __restrict__ hi,
                             half_t* __restrict__ lo) {
    int idx = blockIdx.x * 256 + threadIdx.x;
    if (idx >= H_ * 3584) return;
    int n = idx / 3584;
    int r = idx % 3584;
    int tap = r >> 9, i = r & 511;
    split2(in[n * 3584 + i * 7 + tap], hi + idx, lo + idx);
}

// ---------------------------------------------------------------------------
// Row-wise LayerNorm over H=384 (fp32 in/out, in-place safe), one wave per row
// ---------------------------------------------------------------------------
__global__ void k_ln(const float* __restrict__ in, float* __restrict__ out,
                     const float* __restrict__ g, const float* __restrict__ b) {
    int row = blockIdx.x;
    int lane = threadIdx.x;
    const float* ir = in + (long)row * H_;
    float v[6];
    float s = 0.f;
#pragma unroll
    for (int j = 0; j < 6; ++j) { v[j] = ir[lane + (j << 6)]; s += v[j]; }
#pragma unroll
    for (int o = 32; o > 0; o >>= 1) s += __shfl_down(s, o, 64);
    s = __shfl(s, 0, 64);
    float mean = s * (1.f / 384.f);
    float q = 0.f;
#pragma unroll
    for (int j = 0; j < 6; ++j) { float d = v[j] - mean; q += d * d; }
#pragma unroll
    for (int o = 32; o > 0; o >>= 1) q += __shfl_down(q, o, 64);
    q = __shfl(q, 0, 64);
    float rstd = rsqrtf(q * (1.f / 384.f) + 1e-5f);
    float* orow = out + (long)row * H_;
#pragma unroll
    for (int j = 0; j < 6; ++j) {
        int c = lane + (j << 6);
        orow[c] = (v[j] - mean) * rstd * g[c] + b[c];
    }
}

// ---------------------------------------------------------------------------
// Fused depthwise conv (k=7, pad=3) + LayerNorm; emits fp16 hi/lo for GEMM1
// 4 rows per block (one per wave) so the 7-tap t-overlap is L1-resident.
// ---------------------------------------------------------------------------
__global__ __launch_bounds__(256) void k_dwconv_ln(
    const float* __restrict__ h, half_t* __restrict__ oh,
    half_t* __restrict__ ol,
    const float* __restrict__ w, const float* __restrict__ wb,
    const float* __restrict__ g, const float* __restrict__ gb) {
    int row = (blockIdx.x << 2) + (threadIdx.x >> 6);
    int b = row >> 11;
    int t = row & 2047;
    int lane = threadIdx.x & 63;
    const float* hb = h + ((long)b * T_) * H_;
    float v[6];
    float s = 0.f;
#pragma unroll
    for (int j = 0; j < 6; ++j) {
        int c = lane + (j << 6);
        float acc = wb[c];
        const float* wc = w + c * 7;
#pragma unroll
        for (int k = 0; k < 7; ++k) {
            int tt = t + k - 3;
            if ((unsigned)tt < (unsigned)T_)
                acc = fmaf(hb[(long)tt * H_ + c], wc[k], acc);
        }
        v[j] = acc;
        s += acc;
    }
#pragma unroll
    for (int o = 32; o > 0; o >>= 1) s += __shfl_down(s, o, 64);
    s = __shfl(s, 0, 64);
    float mean = s * (1.f / 384.f);
    float q = 0.f;
#pragma unroll
    for (int j = 0; j < 6; ++j) { float d = v[j] - mean; q += d * d; }
#pragma unroll
    for (int o = 32; o > 0; o >>= 1) q += __shfl_down(q, o, 64);
    q = __shfl(q, 0, 64);
    float rstd = rsqrtf(q * (1.f / 384.f) + 1e-5f);
    long ro = (long)row * H_;
#pragma unroll
    for (int j = 0; j < 6; ++j) {
        int c = lane + (j << 6);
        float val = (v[j] - mean) * rstd * g[c] + gb[c];
        split2(val, oh + ro + c, ol + ro + c);
    }
}

// ---------------------------------------------------------------------------
// Prefetch register sets as NAMED float4s via macros (never a struct/reference:
// round-1 regression traced to struct-by-ref prefetch sets getting scratch-
// allocated -> ~1 GB of spill traffic; rule: everything SROA-able).
// ---------------------------------------------------------------------------
#define DECLSET(S) float4 pAh##S, pAl##S, pBh0##S, pBl0##S, pBh1##S, pBl1##S

#define LOADREGS(S, k0_) do {                                               \
    int k0v = (k0_);                                                        \
    if (MODE == 0) {                                                        \
        int kk = k0v + ak;                                                  \
        int tap = kk >> 9, ii = kk & 511;                                   \
        int ta = tt0 + tap;                                                 \
        pAh##S = pAl##S = make_float4(0.f, 0.f, 0.f, 0.f);                  \
        if ((unsigned)ta < 2048u) {                                         \
            long o = ((long)bq * 2048 + ta) * 512 + ii;                     \
            pAh##S = *(const float4*)(Ah + o);                              \
            pAl##S = *(const float4*)(Al + o);                              \
        }                                                                   \
    } else {                                                                \
        pAh##S = *(const float4*)(Ah + aoff + k0v);                         \
        pAl##S = *(const float4*)(Al + aoff + k0v);                         \
    }                                                                       \
    pBh0##S = *(const float4*)(Bh + boff0 + k0v);                           \
    pBl0##S = *(const float4*)(Bl + boff0 + k0v);                           \
    pBh1##S = *(const float4*)(Bh + boff1 + k0v);                           \
    pBl1##S = *(const float4*)(Bl + boff1 + k0v);                           \
} while (0)

#define STOREBUF(S, buf) do {                                               \
    *(float4*)&smem[(buf) * 2048 + aw] = pAh##S;                            \
    *(float4*)&smem[4096 + (buf) * 2048 + aw] = pAl##S;                     \
    int b_ = 8192 + (buf) * 4096 + aw;                                      \
    *(float4*)&smem[b_] = pBh0##S;                                          \
    *(float4*)&smem[b_ + 2048] = pBh1##S;                                   \
    *(float4*)&smem[b_ + 8192] = pBl0##S;                                   \
    *(float4*)&smem[b_ + 8192 + 2048] = pBl1##S;                            \
} while (0)

// ---------------------------------------------------------------------------
// MFMA fp16x3 GEMM, BM=64 x BN=128, BK=32, 256 threads = 4 waves of 64x32
// wave tile (4x2 frags 16x16x32). 48 KB LDS -> 3 blocks/CU.
// Tile order: XCD-chunked (bijective, nwg%8==0), n-fastest within a chunk ->
// each XCD owns a contiguous run of m-tiles across ALL n-tiles: A is fetched
// into exactly one XCD L2 (read once chip-wide), B stays L2-resident.
// Swizzle: granule position (g ^ (row>>1))&3 -> conflict-free store AND read
// (verified round 1: SQ_LDS_BANK_CONFLICT 1.65e7 -> 0).
// 2-deep global prefetch (named register sets), single lgkm barrier/K-step.
// nIter must be EVEN (K in {3584, 384, 1536} -> 112/12/48).
// MODE 0: A = x im2row (K=3584), +bias, fp32 out
// MODE 1: +bias, exact GELU, fp16 hi/lo out (smem round-trip for coalescing)
// MODE 2: +bias, +res, fp32 out
// LDS halves layout: Ah buf*2048 | Al 4096+buf*2048 | Bh 8192+buf*4096
//                    | Bl 16384+buf*4096   (total 24576 halves = 48 KB)
// ---------------------------------------------------------------------------
template <int MODE, int NN>
__global__ __launch_bounds__(256, 3) void k_mgemm64(
    const half_t* __restrict__ Ah, const half_t* __restrict__ Al,
    const half_t* __restrict__ Bh, const half_t* __restrict__ Bl,
    const float* __restrict__ bias, const float* __restrict__ res,
    float* __restrict__ Cf, half_t* __restrict__ Ch, half_t* __restrict__ Cl,
    int N, int K) {
    __shared__ __align__(16) half_t smem[24576];
    const int tid = threadIdx.x;
    const int lane = tid & 63, wid = tid >> 6;
    const int wn = wid << 5;
    const int quad = lane >> 4, l16 = lane & 15;

    // XCD-chunked tile mapping: consecutive blockIdx round-robin XCDs, so
    // (lin&7) is the XCD; give each a contiguous n-fastest run of tiles.
    constexpr int NWG = 256 * NN;
    constexpr int CHUNK = NWG / 8;
    const int lin = blockIdx.x;
    const int tile = (lin & 7) * CHUNK + (lin >> 3);
    const int m0 = (tile / NN) << 6;
    const int n0 = (tile % NN) << 7;

    const int ar = tid >> 2;          // staging row 0..63
    const int ak = (tid & 3) << 3;    // k offset (halves), granule = tid&3

    long aoff = 0;
    int tt0 = 0, bq = 0;
    if (MODE == 0) {
        bq = m0 >> 11;
        tt0 = (m0 & 2047) + ar - 3;
    } else {
        aoff = (long)(m0 + ar) * K + ak;
    }
    const long boff0 = (long)(n0 + ar) * K + ak;
    const long boff1 = boff0 + (long)64 * K;

    // swizzled staging position: granule g stored at (g ^ (row>>1)) & 3
    const int aw = ar * 32 + ((((tid & 3) ^ (ar >> 1)) & 3) << 3);

    DECLSET(0);
    DECLSET(1);

    f32x4 acc1[4][2] = {};
    f32x4 acc2[4][2] = {};
    // read-side swizzle: position (quad ^ (row>>1))&3 recovers granule quad
    const int sw = ((quad ^ (l16 >> 1)) & 3) << 3;

    auto compute = [&](int buf) {
        const int ab = buf * 2048 + l16 * 32 + sw;
        const int bb = 8192 + buf * 4096 + (wn + l16) * 32 + sw;
        f16x8 fah[4], fal[4], fgh[2], fgl[2];
#pragma unroll
        for (int f = 0; f < 4; ++f) {
            fah[f] = *(const f16x8*)&smem[ab + f * 512];
            fal[f] = *(const f16x8*)&smem[ab + 4096 + f * 512];
        }
#pragma unroll
        for (int g = 0; g < 2; ++g) {
            fgh[g] = *(const f16x8*)&smem[bb + g * 512];
            fgl[g] = *(const f16x8*)&smem[bb + 8192 + g * 512];
        }
#pragma unroll
        for (int f = 0; f < 4; ++f)
#pragma unroll
            for (int g = 0; g < 2; ++g)
                acc2[f][g] = __builtin_amdgcn_mfma_f32_16x16x32_f16(fah[f], fgl[g], acc2[f][g], 0, 0, 0);
#pragma unroll
        for (int f = 0; f < 4; ++f)
#pragma unroll
            for (int g = 0; g < 2; ++g)
                acc2[f][g] = __builtin_amdgcn_mfma_f32_16x16x32_f16(fal[f], fgh[g], acc2[f][g], 0, 0, 0);
#pragma unroll
        for (int f = 0; f < 4; ++f)
#pragma unroll
            for (int g = 0; g < 2; ++g)
                acc1[f][g] = __builtin_amdgcn_mfma_f32_16x16x32_f16(fah[f], fgh[g], acc1[f][g], 0, 0, 0);
    };

    const int nIter = K >> 5;
    // prologue: set0 <- tile0, set1 <- tile1, stage tile0, set0 <- tile2
    LOADREGS(0, 0);
    LOADREGS(1, 32);
    STOREBUF(0, 0);
    if (nIter > 2) LOADREGS(0, 64);
    // steady state (even it): buf0 = tile it, set1 = tile it+1, set0 = it+2
    for (int it = 0; it < nIter; it += 2) {
        lds_barrier();
        compute(0);
        STOREBUF(1, 1);
        if (it + 3 < nIter) LOADREGS(1, (it + 3) << 5);
        lds_barrier();
        compute(1);
        if (it + 2 < nIter) {
            STOREBUF(0, 0);
            if (it + 4 < nIter) LOADREGS(0, (it + 4) << 5);
        }
    }

    float bv[2];
    bv[0] = bias[n0 + wn + l16];
    bv[1] = bias[n0 + wn + 16 + l16];

    if (MODE == 1) {
        // GELU + fp16 hi/lo split, smem round-trip for coalesced stores.
        // Planes: hi @0, lo @8704, row stride 136 halves.
        __syncthreads();
#pragma unroll
        for (int f = 0; f < 4; ++f)
#pragma unroll
            for (int g = 0; g < 2; ++g)
#pragma unroll
                for (int r = 0; r < 4; ++r) {
                    int rm = f * 16 + quad * 4 + r;
                    int cn = wn + g * 16 + l16;
                    float v = acc1[f][g][r] + acc2[f][g][r] * LO_INV + bv[g];
                    v = 0.5f * v * (1.0f + erff(v * 0.70710678118654752f));
                    half_t hh = (half_t)v;
                    smem[rm * 136 + cn] = hh;
                    smem[8704 + rm * 136 + cn] = (half_t)((v - (float)hh) * LO_SCALE);
                }
        __syncthreads();
        int row = tid >> 2, c0 = (tid & 3) << 5;
        long go = (long)(m0 + row) * N + n0 + c0;
        int so = row * 136 + c0;
#pragma unroll
        for (int u = 0; u < 4; ++u) {
            *(float4*)(Ch + go + u * 8) = *(const float4*)&smem[so + u * 8];
            *(float4*)(Cl + go + u * 8) = *(const float4*)&smem[8704 + so + u * 8];
        }
    } else {
#pragma unroll
        for (int f = 0; f < 4; ++f)
#pragma unroll
            for (int g = 0; g < 2; ++g)
#pragma unroll
                for (int r = 0; r < 4; ++r) {
                    long row = m0 + f * 16 + quad * 4 + r;
                    int col = n0 + wn + g * 16 + l16;
                    float v = acc1[f][g][r] + acc2[f][g][r] * LO_INV + bv[g];
                    long o = row * N + col;
                    if (MODE == 2) v += res[o];
                    Cf[o] = v;
                }
    }
}

// ---------------------------------------------------------------------------
// Fused out-conv (pointwise, C=8) + nearest-embedding argmin over K=8192
// ---------------------------------------------------------------------------
__global__ __launch_bounds__(256) void k_outconv_argmin(
    const float* __restrict__ h, const float* __restrict__ ow,
    const float* __restrict__ ob, const float* __restrict__ emb,
    int* __restrict__ outIdx) {
    __shared__ float hs[16][H_ + 1];
    __shared__ float zs[16][8];
    __shared__ float es[16 * 516];
    __shared__ float rb[16][16];
    __shared__ int ri[16][16];
    const int tid = threadIdx.x;
    const int row0 = blockIdx.x << 4;

    for (int i = tid; i < 16 * (H_ / 4); i += 256) {
        int r = i / 96;
        int c4 = (i % 96) << 2;
        float4 v = *(const float4*)&h[((long)(row0 + r)) * H_ + c4];
        hs[r][c4] = v.x; hs[r][c4 + 1] = v.y; hs[r][c4 + 2] = v.z; hs[r][c4 + 3] = v.w;
    }
    __syncthreads();

    if (tid < 128) {
        int r = tid & 15, c = tid >> 4;
        float acc = ob[c];
        const float* wc = ow + c * H_;
        for (int j = 0; j < H_; ++j) acc = fmaf(hs[r][j], wc[j], acc);
        zs[r][c] = acc;
    }
    __syncthreads();

    const int r = tid & 15;
    const int sl = tid >> 4;
    float z0 = zs[r][0], z1 = zs[r][1], z2 = zs[r][2], z3 = zs[r][3];
    float z4 = zs[r][4], z5 = zs[r][5], z6 = zs[r][6], z7 = zs[r][7];
    float best = 3.4e38f;
    int bi = 0;

    for (int ch = 0; ch < 8; ++ch) {
        __syncthreads();
        for (int i = tid; i < 2048; i += 256) {
            int e = i >> 1;
            int half = (i & 1) << 2;
            float4 src = *(const float4*)&emb[(((long)(ch << 10)) + e) * 8 + half];
            *(float4*)&es[(e >> 6) * 516 + ((e & 63) << 3) + half] = src;
        }
        __syncthreads();
        const float* ep = es + sl * 516;
        int gbase = (ch << 10) + (sl << 6);
#pragma unroll 4
        for (int j = 0; j < 64; ++j) {
            float4 e0 = *(const float4*)(ep + (j << 3));
            float4 e1 = *(const float4*)(ep + (j << 3) + 4);
            float t, d;
            t = e0.x - z0; d = t * t;
            t = e0.y - z1; d = fmaf(t, t, d);
            t = e0.z - z2; d = fmaf(t, t, d);
            t = e0.w - z3; d = fmaf(t, t, d);
            t = e1.x - z4; d = fmaf(t, t, d);
            t = e1.y - z5; d = fmaf(t, t, d);
            t = e1.z - z6; d = fmaf(t, t, d);
            t = e1.w - z7; d = fmaf(t, t, d);
            if (d < best) { best = d; bi = gbase + j; }
        }
    }
    rb[r][sl] = best;
    ri[r][sl] = bi;
    __syncthreads();
    if (sl == 0) {
        float bb = rb[r][0];
        int bbi = ri[r][0];
#pragma unroll
        for (int s2 = 1; s2 < 16; ++s2) {
            float v = rb[r][s2];
            int i2 = ri[r][s2];
            if (v < bb || (v == bb && i2 < bbi)) { bb = v; bbi = i2; }
        }
        outIdx[row0 + r] = bbi;
    }
}

// ---------------------------------------------------------------------------
// host launcher
// ---------------------------------------------------------------------------
extern "C" void kernel_launch(void* const* d_in, const int* in_sizes, int n_in,
                              void* d_out, int out_size, void* d_ws, size_t ws_size,
                              hipStream_t stream) {
    const float* x        = (const float*)d_in[0];
    const float* enc_w    = (const float*)d_in[1];
    const float* enc_b    = (const float*)d_in[2];
    const float* enc_ln_g = (const float*)d_in[3];
    const float* enc_ln_b = (const float*)d_in[4];
    const float* blk_dw_w = (const float*)d_in[5];
    const float* blk_dw_b = (const float*)d_in[6];
    const float* blk_ln_g = (const float*)d_in[7];
    const float* blk_ln_b = (const float*)d_in[8];
    const float* blk_w1   = (const float*)d_in[9];
    const float* blk_b1   = (const float*)d_in[10];
    const float* blk_w2   = (const float*)d_in[11];
    const float* blk_b2   = (const float*)d_in[12];
    const float* out_w    = (const float*)d_in[13];
    const float* out_b    = (const float*)d_in[14];
    const float* emb      = (const float*)d_in[15];
    int* out = (int*)d_out;

    char* base = (char*)d_ws;
    float*  h    = (float*)base;                       // 25165824 B
    half_t* tmph = (half_t*)(base + 25165824);         // 12582912 B
    half_t* tmpl = (half_t*)(base + 37748736);         // 12582912 B
    half_t* ht4h = (half_t*)(base + 50331648);         // 50331648 B
    half_t* ht4l = (half_t*)(base + 100663296);        // 50331648 B
    half_t* ench = (half_t*)(base + 150994944);        // 2752512 B
    half_t* encl = (half_t*)(base + 153747456);        // 2752512 B
    half_t* w1h  = (half_t*)(base + 156499968);        // 7077888 B
    half_t* w1l  = (half_t*)(base + 163577856);        // 7077888 B
    half_t* w2h  = (half_t*)(base + 170655744);        // 7077888 B
    half_t* w2l  = (half_t*)(base + 177733632);        // 7077888 B
    // x hi/lo alias the ht4 region (dead until first GEMM1)
    half_t* xh = ht4h;                                  // 16777216 B
    half_t* xl = (half_t*)(base + 50331648 + 16777216); // 16777216 B

    k_split<<<(8388608 + 255) / 256, 256, 0, stream>>>(x, xh, xl, 8388608L);
    k_split<<<(3538944 + 255) / 256, 256, 0, stream>>>(blk_w1, w1h, w1l, 3538944L);
    k_split<<<(3538944 + 255) / 256, 256, 0, stream>>>(blk_w2, w2h, w2l, 3538944L);
    k_split_encw<<<(H_ * 3584 + 255) / 256, 256, 0, stream>>>(enc_w, ench, encl);

    // encoder conv (im2row MFMA GEMM) -> h, then in-place LN
    k_mgemm64<0, 3><<<768, 256, 0, stream>>>(xh, xl, ench, encl, enc_b,
                                             nullptr, h, nullptr, nullptr,
                                             H_, 3584);
    k_ln<<<BT_, 64, 0, stream>>>(h, h, enc_ln_g, enc_ln_b);

    for (int i = 0; i < 6; ++i) {
        k_dwconv_ln<<<BT_ / 4, 256, 0, stream>>>(h, tmph, tmpl, blk_dw_w + i * H_ * 7,
                                                 blk_dw_b + i * H_, blk_ln_g + i * H_,
                                                 blk_ln_b + i * H_);
        k_mgemm64<1, 12><<<3072, 256, 0, stream>>>(
            tmph, tmpl, w1h + (long)i * 589824, w1l + (long)i * 589824,
            blk_b1 + i * H4_, nullptr, nullptr, ht4h, ht4l, H4_, H_);
        k_mgemm64<2, 3><<<768, 256, 0, stream>>>(
            ht4h, ht4l, w2h + (long)i * 589824, w2l + (long)i * 589824,
            blk_b2 + i * H_, h, h, nullptr, nullptr, H_, H4_);
    }

    k_outconv_argmin<<<BT_ / 16, 256, 0, stream>>>(h, out_w, out_b, emb, out);
}

// Round 3
// 1664.652 us; speedup vs baseline: 2.5288x; 1.0221x over previous
//
#include <hip/hip_runtime.h>
#include <math.h>

#define T_   2048
#define DIN  512
#define H_   384
#define H4_  1536
#define BT_  16384

typedef _Float16 half_t;
typedef _Float16 f16x8 __attribute__((ext_vector_type(8)));
typedef float f32x4 __attribute__((ext_vector_type(4)));

#define LO_SCALE 2048.0f
#define LO_INV   4.8828125e-4f

// lgkm-only barrier: prefetched global->VGPR loads stay in flight across it.
__device__ __forceinline__ void lds_barrier() {
    asm volatile("s_waitcnt lgkmcnt(0)\n\ts_barrier" ::: "memory");
}

__device__ __forceinline__ void split2(float v, half_t* hi, half_t* lo) {
    half_t h = (half_t)v;
    *hi = h;
    *lo = (half_t)((v - (float)h) * LO_SCALE);
}

// ---------------------------------------------------------------------------
// fp32 -> (hi, lo*2048) fp16 element-wise split
// ---------------------------------------------------------------------------
__global__ void k_split(const float* __restrict__ in, half_t* __restrict__ hi,
                        half_t* __restrict__ lo, long n) {
    long i = (long)blockIdx.x * 256 + threadIdx.x;
    if (i >= n) return;
    split2(in[i], hi + i, lo + i);
}

// enc_w [H][DIN][7] -> [H][tap*512+i] hi/lo
__global__ void k_split_encw(const float* __restrict__ in, half_t* __restrict__ hi,
                             half_t* __restrict__ lo) {
    int idx = blockIdx.x * 256 + threadIdx.x;
    if (idx >= H_ * 3584) return;
    int n = idx / 3584;
    int r = idx % 3584;
    int tap = r >> 9, i = r & 511;
    split2(in[n * 3584 + i * 7 + tap], hi + idx, lo + idx);
}

// ---------------------------------------------------------------------------
// Row-wise LayerNorm over H=384 (fp32 in/out, in-place safe), one wave per row
// ---------------------------------------------------------------------------
__global__ void k_ln(const float* __restrict__ in, float* __restrict__ out,
                     const float* __restrict__ g, const float* __restrict__ b) {
    int row = blockIdx.x;
    int lane = threadIdx.x;
    const float* ir = in + (long)row * H_;
    float v[6];
    float s = 0.f;
#pragma unroll
    for (int j = 0; j < 6; ++j) { v[j] = ir[lane + (j << 6)]; s += v[j]; }
#pragma unroll
    for (int o = 32; o > 0; o >>= 1) s += __shfl_down(s, o, 64);
    s = __shfl(s, 0, 64);
    float mean = s * (1.f / 384.f);
    float q = 0.f;
#pragma unroll
    for (int j = 0; j < 6; ++j) { float d = v[j] - mean; q += d * d; }
#pragma unroll
    for (int o = 32; o > 0; o >>= 1) q += __shfl_down(q, o, 64);
    q = __shfl(q, 0, 64);
    float rstd = rsqrtf(q * (1.f / 384.f) + 1e-5f);
    float* orow = out + (long)row * H_;
#pragma unroll
    for (int j = 0; j < 6; ++j) {
        int c = lane + (j << 6);
        orow[c] = (v[j] - mean) * rstd * g[c] + b[c];
    }
}

// ---------------------------------------------------------------------------
// Fused depthwise conv (k=7, pad=3) + LayerNorm; emits fp16 hi/lo for GEMM1
// ---------------------------------------------------------------------------
__global__ __launch_bounds__(256) void k_dwconv_ln(
    const float* __restrict__ h, half_t* __restrict__ oh,
    half_t* __restrict__ ol,
    const float* __restrict__ w, const float* __restrict__ wb,
    const float* __restrict__ g, const float* __restrict__ gb) {
    int row = (blockIdx.x << 2) + (threadIdx.x >> 6);
    int b = row >> 11;
    int t = row & 2047;
    int lane = threadIdx.x & 63;
    const float* hb = h + ((long)b * T_) * H_;
    float v[6];
    float s = 0.f;
#pragma unroll
    for (int j = 0; j < 6; ++j) {
        int c = lane + (j << 6);
        float acc = wb[c];
        const float* wc = w + c * 7;
#pragma unroll
        for (int k = 0; k < 7; ++k) {
            int tt = t + k - 3;
            if ((unsigned)tt < (unsigned)T_)
                acc = fmaf(hb[(long)tt * H_ + c], wc[k], acc);
        }
        v[j] = acc;
        s += acc;
    }
#pragma unroll
    for (int o = 32; o > 0; o >>= 1) s += __shfl_down(s, o, 64);
    s = __shfl(s, 0, 64);
    float mean = s * (1.f / 384.f);
    float q = 0.f;
#pragma unroll
    for (int j = 0; j < 6; ++j) { float d = v[j] - mean; q += d * d; }
#pragma unroll
    for (int o = 32; o > 0; o >>= 1) q += __shfl_down(q, o, 64);
    q = __shfl(q, 0, 64);
    float rstd = rsqrtf(q * (1.f / 384.f) + 1e-5f);
    long ro = (long)row * H_;
#pragma unroll
    for (int j = 0; j < 6; ++j) {
        int c = lane + (j << 6);
        float val = (v[j] - mean) * rstd * g[c] + gb[c];
        split2(val, oh + ro + c, ol + ro + c);
    }
}

// ---------------------------------------------------------------------------
// Prefetch register sets as NAMED float4s via macros (never struct/reference —
// round-1: address-taken sets scratch-spill; rule #20).
// ---------------------------------------------------------------------------
#define DECLSET(S) float4 pAh##S, pAl##S, pBh0##S, pBl0##S, pBh1##S, pBl1##S

#define LOADREGS(S, k0_) do {                                               \
    int k0v = (k0_);                                                        \
    if (MODE == 0) {                                                        \
        int kk = k0v + ak;                                                  \
        int tap = kk >> 9, ii = kk & 511;                                   \
        int ta = tt0 + tap;                                                 \
        pAh##S = pAl##S = make_float4(0.f, 0.f, 0.f, 0.f);                  \
        if ((unsigned)ta < 2048u) {                                         \
            long o = ((long)bq * 2048 + ta) * 512 + ii;                     \
            pAh##S = *(const float4*)(Ah + o);                              \
            pAl##S = *(const float4*)(Al + o);                              \
        }                                                                   \
    } else {                                                                \
        pAh##S = *(const float4*)(Ah + aoff + k0v);                         \
        pAl##S = *(const float4*)(Al + aoff + k0v);                         \
    }                                                                       \
    pBh0##S = *(const float4*)(Bh + boff0 + k0v);                           \
    pBl0##S = *(const float4*)(Bl + boff0 + k0v);                           \
    pBh1##S = *(const float4*)(Bh + boff1 + k0v);                           \
    pBl1##S = *(const float4*)(Bl + boff1 + k0v);                           \
} while (0)

#define STOREBUF(S, buf) do {                                               \
    *(float4*)&smem[(buf) * 2048 + aw] = pAh##S;                            \
    *(float4*)&smem[4096 + (buf) * 2048 + aw] = pAl##S;                     \
    int b_ = 8192 + (buf) * 4096 + aw;                                      \
    *(float4*)&smem[b_] = pBh0##S;                                          \
    *(float4*)&smem[b_ + 2048] = pBh1##S;                                   \
    *(float4*)&smem[b_ + 8192] = pBl0##S;                                   \
    *(float4*)&smem[b_ + 8192 + 2048] = pBl1##S;                            \
} while (0)

// ---------------------------------------------------------------------------
// MFMA fp16x3 GEMM, BM=64 x BN=128 (used for MODE 0 / encoder im2row only).
// Verified: conflict-free swizzle, XCD-chunked tiles, 2-deep prefetch.
// ---------------------------------------------------------------------------
template <int MODE, int NN>
__global__ __launch_bounds__(256, 3) void k_mgemm64(
    const half_t* __restrict__ Ah, const half_t* __restrict__ Al,
    const half_t* __restrict__ Bh, const half_t* __restrict__ Bl,
    const float* __restrict__ bias, const float* __restrict__ res,
    float* __restrict__ Cf, half_t* __restrict__ Ch, half_t* __restrict__ Cl,
    int N, int K) {
    __shared__ __align__(16) half_t smem[24576];
    const int tid = threadIdx.x;
    const int lane = tid & 63, wid = tid >> 6;
    const int wn = wid << 5;
    const int quad = lane >> 4, l16 = lane & 15;

    constexpr int NWG = 256 * NN;
    constexpr int CHUNK = NWG / 8;
    const int lin = blockIdx.x;
    const int tile = (lin & 7) * CHUNK + (lin >> 3);
    const int m0 = (tile / NN) << 6;
    const int n0 = (tile % NN) << 7;

    const int ar = tid >> 2;
    const int ak = (tid & 3) << 3;

    long aoff = 0;
    int tt0 = 0, bq = 0;
    if (MODE == 0) {
        bq = m0 >> 11;
        tt0 = (m0 & 2047) + ar - 3;
    } else {
        aoff = (long)(m0 + ar) * K + ak;
    }
    const long boff0 = (long)(n0 + ar) * K + ak;
    const long boff1 = boff0 + (long)64 * K;

    const int aw = ar * 32 + ((((tid & 3) ^ (ar >> 1)) & 3) << 3);

    DECLSET(0);
    DECLSET(1);

    f32x4 acc1[4][2] = {};
    f32x4 acc2[4][2] = {};
    const int sw = ((quad ^ (l16 >> 1)) & 3) << 3;

    auto compute = [&](int buf) {
        const int ab = buf * 2048 + l16 * 32 + sw;
        const int bb = 8192 + buf * 4096 + (wn + l16) * 32 + sw;
        f16x8 fah[4], fal[4], fgh[2], fgl[2];
#pragma unroll
        for (int f = 0; f < 4; ++f) {
            fah[f] = *(const f16x8*)&smem[ab + f * 512];
            fal[f] = *(const f16x8*)&smem[ab + 4096 + f * 512];
        }
#pragma unroll
        for (int g = 0; g < 2; ++g) {
            fgh[g] = *(const f16x8*)&smem[bb + g * 512];
            fgl[g] = *(const f16x8*)&smem[bb + 8192 + g * 512];
        }
#pragma unroll
        for (int f = 0; f < 4; ++f)
#pragma unroll
            for (int g = 0; g < 2; ++g)
                acc2[f][g] = __builtin_amdgcn_mfma_f32_16x16x32_f16(fah[f], fgl[g], acc2[f][g], 0, 0, 0);
#pragma unroll
        for (int f = 0; f < 4; ++f)
#pragma unroll
            for (int g = 0; g < 2; ++g)
                acc2[f][g] = __builtin_amdgcn_mfma_f32_16x16x32_f16(fal[f], fgh[g], acc2[f][g], 0, 0, 0);
#pragma unroll
        for (int f = 0; f < 4; ++f)
#pragma unroll
            for (int g = 0; g < 2; ++g)
                acc1[f][g] = __builtin_amdgcn_mfma_f32_16x16x32_f16(fah[f], fgh[g], acc1[f][g], 0, 0, 0);
    };

    const int nIter = K >> 5;
    LOADREGS(0, 0);
    LOADREGS(1, 32);
    STOREBUF(0, 0);
    if (nIter > 2) LOADREGS(0, 64);
    for (int it = 0; it < nIter; it += 2) {
        lds_barrier();
        compute(0);
        STOREBUF(1, 1);
        if (it + 3 < nIter) LOADREGS(1, (it + 3) << 5);
        lds_barrier();
        compute(1);
        if (it + 2 < nIter) {
            STOREBUF(0, 0);
            if (it + 4 < nIter) LOADREGS(0, (it + 4) << 5);
        }
    }

    float bv[2];
    bv[0] = bias[n0 + wn + l16];
    bv[1] = bias[n0 + wn + 16 + l16];

#pragma unroll
    for (int f = 0; f < 4; ++f)
#pragma unroll
        for (int g = 0; g < 2; ++g)
#pragma unroll
            for (int r = 0; r < 4; ++r) {
                long row = m0 + f * 16 + quad * 4 + r;
                int col = n0 + wn + g * 16 + l16;
                float v = acc1[f][g][r] + acc2[f][g][r] * LO_INV + bv[g];
                long o = row * N + col;
                if (MODE == 2) v += res[o];
                Cf[o] = v;
            }
}

// ---------------------------------------------------------------------------
// MFMA fp16x3 GEMM, BM=128 x BN=96, BK=32, 256 threads = 4 waves (2m x 2n),
// wave tile 64x48 (4x3 frags of 16x16x32) -> 36 MFMA/wave/K-step, 25% fewer
// LDS bytes per FLOP than the 64x128 shape. 56 KB LDS -> 2 blocks/CU;
// acc 96 + frags 56 + 1-deep prefetch ~30 keeps combined regs < 256
// (2 waves/SIMD). Grid fits exactly: MODE2 128x4=512 blk (2/CU), MODE1
// 128x16=2048 (4 rounds). Same verified swizzle family and 1-barrier/K-step
// lgkm-only schedule.
// MODE 1: +bias, exact GELU, fp16 hi/lo out (smem round-trip)
// MODE 2: +bias, +res, fp32 out
// LDS halves per buf: Ah@0(4096) Al@4096 Bh@8192(3072) Bl@11264; BUFSZ 14336.
// ---------------------------------------------------------------------------
#define LOAD96(k0_) do {                                                    \
    int k0v = (k0_);                                                        \
    long a_ = aoff + k0v;                                                   \
    qAh0 = *(const float4*)(Ah + a_);                                       \
    qAh1 = *(const float4*)(Ah + a_ + 8);                                   \
    qAl0 = *(const float4*)(Al + a_);                                       \
    qAl1 = *(const float4*)(Al + a_ + 8);                                   \
    long b_ = boff0 + k0v;                                                  \
    qBh0 = *(const float4*)(Bh + b_);                                       \
    qBl0 = *(const float4*)(Bl + b_);                                       \
    if (tid < 128) {                                                        \
        long c_ = boff1 + k0v;                                              \
        qBh1 = *(const float4*)(Bh + c_);                                   \
        qBl1 = *(const float4*)(Bl + c_);                                   \
    }                                                                       \
} while (0)

#define STORE96(buf) do {                                                   \
    int ab_ = (buf) * 14336 + ra * 32;                                      \
    *(float4*)&smem[ab_ + pa0 * 8] = qAh0;                                  \
    *(float4*)&smem[ab_ + pa1 * 8] = qAh1;                                  \
    *(float4*)&smem[ab_ + 4096 + pa0 * 8] = qAl0;                           \
    *(float4*)&smem[ab_ + 4096 + pa1 * 8] = qAl1;                           \
    int bb_ = (buf) * 14336 + 8192 + rb0 * 32 + pb0 * 8;                    \
    *(float4*)&smem[bb_] = qBh0;                                            \
    *(float4*)&smem[bb_ + 3072] = qBl0;                                     \
    if (tid < 128) {                                                        \
        int bc_ = bb_ + 64 * 32;                                            \
        *(float4*)&smem[bc_] = qBh1;                                        \
        *(float4*)&smem[bc_ + 3072] = qBl1;                                 \
    }                                                                       \
} while (0)

template <int MODE, int NT>
__global__ __launch_bounds__(256, 2) void k_mgemm96(
    const half_t* __restrict__ Ah, const half_t* __restrict__ Al,
    const half_t* __restrict__ Bh, const half_t* __restrict__ Bl,
    const float* __restrict__ bias, const float* __restrict__ res,
    float* __restrict__ Cf, half_t* __restrict__ Ch, half_t* __restrict__ Cl,
    int N, int K) {
    __shared__ __align__(16) half_t smem[28672];
    const int tid = threadIdx.x;
    const int lane = tid & 63, wid = tid >> 6;
    const int wm = (wid >> 1) << 6;       // 0 or 64
    const int wn = (wid & 1) * 48;        // 0 or 48
    const int quad = lane >> 4, l16 = lane & 15;

    // XCD-chunked bijective tile mapping (grid % 8 == 0 for all uses)
    constexpr int NWG = 128 * NT;
    constexpr int CHUNK = NWG / 8;
    const int lin = blockIdx.x;
    const int tile = (lin & 7) * CHUNK + (lin >> 3);
    const int m0 = (tile / NT) << 7;
    const int n0 = (tile % NT) * 96;

    // staging assignment: A: row ra=tid>>1, granules ga0,ga0+1
    //                     B: row rb0=tid>>2 (and rb0+64 for tid<128), gran tid&3
    const int ra = tid >> 1;
    const int ga0 = (tid & 1) << 1;
    const int rb0 = tid >> 2;
    const int gb = tid & 3;
    const int pa0 = (ga0 ^ ((ra >> 1) & 3)) & 3;
    const int pa1 = pa0 ^ 1;
    const int pb0 = (gb ^ ((rb0 >> 1) & 3)) & 3;  // same for rb0+64

    const long aoff = (long)(m0 + ra) * K + (ga0 << 3);
    const long boff0 = (long)(n0 + rb0) * K + (gb << 3);
    const long boff1 = boff0 + (long)64 * K;

    float4 qAh0, qAh1, qAl0, qAl1, qBh0, qBl0, qBh1, qBl1;

    f32x4 acc1[4][3] = {};
    f32x4 acc2[4][3] = {};
    const int sw = ((quad ^ (l16 >> 1)) & 3) << 3;

    auto compute = [&](int buf) {
        const int ab = buf * 14336 + (wm + l16) * 32 + sw;
        const int bb = buf * 14336 + 8192 + (wn + l16) * 32 + sw;
        f16x8 fah[4], fal[4], fgh[3], fgl[3];
#pragma unroll
        for (int f = 0; f < 4; ++f) {
            fah[f] = *(const f16x8*)&smem[ab + f * 512];
            fal[f] = *(const f16x8*)&smem[ab + 4096 + f * 512];
        }
#pragma unroll
        for (int g = 0; g < 3; ++g) {
            fgh[g] = *(const f16x8*)&smem[bb + g * 512];
            fgl[g] = *(const f16x8*)&smem[bb + 3072 + g * 512];
        }
#pragma unroll
        for (int f = 0; f < 4; ++f)
#pragma unroll
            for (int g = 0; g < 3; ++g)
                acc2[f][g] = __builtin_amdgcn_mfma_f32_16x16x32_f16(fah[f], fgl[g], acc2[f][g], 0, 0, 0);
#pragma unroll
        for (int f = 0; f < 4; ++f)
#pragma unroll
            for (int g = 0; g < 3; ++g)
                acc2[f][g] = __builtin_amdgcn_mfma_f32_16x16x32_f16(fal[f], fgh[g], acc2[f][g], 0, 0, 0);
#pragma unroll
        for (int f = 0; f < 4; ++f)
#pragma unroll
            for (int g = 0; g < 3; ++g)
                acc1[f][g] = __builtin_amdgcn_mfma_f32_16x16x32_f16(fah[f], fgh[g], acc1[f][g], 0, 0, 0);
    };

    const int nIter = K >> 5;
    LOAD96(0);
    STORE96(0);
    int cur = 0;
    for (int it = 0; it < nIter; ++it) {
        if (it + 1 < nIter) LOAD96((it + 1) << 5);
        lds_barrier();
        compute(cur);
        if (it + 1 < nIter) STORE96(cur ^ 1);
        cur ^= 1;
    }

    float bv[3];
#pragma unroll
    for (int g = 0; g < 3; ++g) bv[g] = bias[n0 + wn + g * 16 + l16];

    if (MODE == 1) {
        // GELU + fp16 hi/lo split; smem round-trip, plane stride 104 halves,
        // hi @0, lo @13312 (= 128*104). 26624 halves <= 28672.
        __syncthreads();
#pragma unroll
        for (int f = 0; f < 4; ++f)
#pragma unroll
            for (int g = 0; g < 3; ++g)
#pragma unroll
                for (int r = 0; r < 4; ++r) {
                    int rm = wm + f * 16 + quad * 4 + r;
                    int cn = wn + g * 16 + l16;
                    float v = acc1[f][g][r] + acc2[f][g][r] * LO_INV + bv[g];
                    v = 0.5f * v * (1.0f + erff(v * 0.70710678118654752f));
                    half_t hh = (half_t)v;
                    smem[rm * 104 + cn] = hh;
                    smem[13312 + rm * 104 + cn] = (half_t)((v - (float)hh) * LO_SCALE);
                }
        __syncthreads();
        int row = tid >> 1, c0 = (tid & 1) * 48;
        long go = (long)(m0 + row) * N + n0 + c0;
        int so = row * 104 + c0;
#pragma unroll
        for (int u = 0; u < 6; ++u) {
            *(float4*)(Ch + go + u * 8) = *(const float4*)&smem[so + u * 8];
            *(float4*)(Cl + go + u * 8) = *(const float4*)&smem[13312 + so + u * 8];
        }
    } else {
#pragma unroll
        for (int f = 0; f < 4; ++f)
#pragma unroll
            for (int g = 0; g < 3; ++g)
#pragma unroll
                for (int r = 0; r < 4; ++r) {
                    long row = m0 + wm + f * 16 + quad * 4 + r;
                    int col = n0 + wn + g * 16 + l16;
                    float v = acc1[f][g][r] + acc2[f][g][r] * LO_INV + bv[g];
                    long o = row * N + col;
                    v += res[o];
                    Cf[o] = v;
                }
    }
}

// ---------------------------------------------------------------------------
// Fused out-conv (pointwise, C=8) + nearest-embedding argmin over K=8192
// ---------------------------------------------------------------------------
__global__ __launch_bounds__(256) void k_outconv_argmin(
    const float* __restrict__ h, const float* __restrict__ ow,
    const float* __restrict__ ob, const float* __restrict__ emb,
    int* __restrict__ outIdx) {
    __shared__ float hs[16][H_ + 1];
    __shared__ float zs[16][8];
    __shared__ float es[16 * 516];
    __shared__ float rb[16][16];
    __shared__ int ri[16][16];
    const int tid = threadIdx.x;
    const int row0 = blockIdx.x << 4;

    for (int i = tid; i < 16 * (H_ / 4); i += 256) {
        int r = i / 96;
        int c4 = (i % 96) << 2;
        float4 v = *(const float4*)&h[((long)(row0 + r)) * H_ + c4];
        hs[r][c4] = v.x; hs[r][c4 + 1] = v.y; hs[r][c4 + 2] = v.z; hs[r][c4 + 3] = v.w;
    }
    __syncthreads();

    if (tid < 128) {
        int r = tid & 15, c = tid >> 4;
        float acc = ob[c];
        const float* wc = ow + c * H_;
        for (int j = 0; j < H_; ++j) acc = fmaf(hs[r][j], wc[j], acc);
        zs[r][c] = acc;
    }
    __syncthreads();

    const int r = tid & 15;
    const int sl = tid >> 4;
    float z0 = zs[r][0], z1 = zs[r][1], z2 = zs[r][2], z3 = zs[r][3];
    float z4 = zs[r][4], z5 = zs[r][5], z6 = zs[r][6], z7 = zs[r][7];
    float best = 3.4e38f;
    int bi = 0;

    for (int ch = 0; ch < 8; ++ch) {
        __syncthreads();
        for (int i = tid; i < 2048; i += 256) {
            int e = i >> 1;
            int half = (i & 1) << 2;
            float4 src = *(const float4*)&emb[(((long)(ch << 10)) + e) * 8 + half];
            *(float4*)&es[(e >> 6) * 516 + ((e & 63) << 3) + half] = src;
        }
        __syncthreads();
        const float* ep = es + sl * 516;
        int gbase = (ch << 10) + (sl << 6);
#pragma unroll 4
        for (int j = 0; j < 64; ++j) {
            float4 e0 = *(const float4*)(ep + (j << 3));
            float4 e1 = *(const float4*)(ep + (j << 3) + 4);
            float t, d;
            t = e0.x - z0; d = t * t;
            t = e0.y - z1; d = fmaf(t, t, d);
            t = e0.z - z2; d = fmaf(t, t, d);
            t = e0.w - z3; d = fmaf(t, t, d);
            t = e1.x - z4; d = fmaf(t, t, d);
            t = e1.y - z5; d = fmaf(t, t, d);
            t = e1.z - z6; d = fmaf(t, t, d);
            t = e1.w - z7; d = fmaf(t, t, d);
            if (d < best) { best = d; bi = gbase + j; }
        }
    }
    rb[r][sl] = best;
    ri[r][sl] = bi;
    __syncthreads();
    if (sl == 0) {
        float bb = rb[r][0];
        int bbi = ri[r][0];
#pragma unroll
        for (int s2 = 1; s2 < 16; ++s2) {
            float v = rb[r][s2];
            int i2 = ri[r][s2];
            if (v < bb || (v == bb && i2 < bbi)) { bb = v; bbi = i2; }
        }
        outIdx[row0 + r] = bbi;
    }
}

// ---------------------------------------------------------------------------
// host launcher
// ---------------------------------------------------------------------------
extern "C" void kernel_launch(void* const* d_in, const int* in_sizes, int n_in,
                              void* d_out, int out_size, void* d_ws, size_t ws_size,
                              hipStream_t stream) {
    const float* x        = (const float*)d_in[0];
    const float* enc_w    = (const float*)d_in[1];
    const float* enc_b    = (const float*)d_in[2];
    const float* enc_ln_g = (const float*)d_in[3];
    const float* enc_ln_b = (const float*)d_in[4];
    const float* blk_dw_w = (const float*)d_in[5];
    const float* blk_dw_b = (const float*)d_in[6];
    const float* blk_ln_g = (const float*)d_in[7];
    const float* blk_ln_b = (const float*)d_in[8];
    const float* blk_w1   = (const float*)d_in[9];
    const float* blk_b1   = (const float*)d_in[10];
    const float* blk_w2   = (const float*)d_in[11];
    const float* blk_b2   = (const float*)d_in[12];
    const float* out_w    = (const float*)d_in[13];
    const float* out_b    = (const float*)d_in[14];
    const float* emb      = (const float*)d_in[15];
    int* out = (int*)d_out;

    char* base = (char*)d_ws;
    float*  h    = (float*)base;                       // 25165824 B
    half_t* tmph = (half_t*)(base + 25165824);         // 12582912 B
    half_t* tmpl = (half_t*)(base + 37748736);         // 12582912 B
    half_t* ht4h = (half_t*)(base + 50331648);         // 50331648 B
    half_t* ht4l = (half_t*)(base + 100663296);        // 50331648 B
    half_t* ench = (half_t*)(base + 150994944);        // 2752512 B
    half_t* encl = (half_t*)(base + 153747456);        // 2752512 B
    half_t* w1h  = (half_t*)(base + 156499968);        // 7077888 B
    half_t* w1l  = (half_t*)(base + 163577856);        // 7077888 B
    half_t* w2h  = (half_t*)(base + 170655744);        // 7077888 B
    half_t* w2l  = (half_t*)(base + 177733632);        // 7077888 B
    // x hi/lo alias the ht4 region (dead until first GEMM1)
    half_t* xh = ht4h;                                  // 16777216 B
    half_t* xl = (half_t*)(base + 50331648 + 16777216); // 16777216 B

    k_split<<<(8388608 + 255) / 256, 256, 0, stream>>>(x, xh, xl, 8388608L);
    k_split<<<(3538944 + 255) / 256, 256, 0, stream>>>(blk_w1, w1h, w1l, 3538944L);
    k_split<<<(3538944 + 255) / 256, 256, 0, stream>>>(blk_w2, w2h, w2l, 3538944L);
    k_split_encw<<<(H_ * 3584 + 255) / 256, 256, 0, stream>>>(enc_w, ench, encl);

    // encoder conv (im2row MFMA GEMM) -> h, then in-place LN
    k_mgemm64<0, 3><<<768, 256, 0, stream>>>(xh, xl, ench, encl, enc_b,
                                             nullptr, h, nullptr, nullptr,
                                             H_, 3584);
    k_ln<<<BT_, 64, 0, stream>>>(h, h, enc_ln_g, enc_ln_b);

    for (int i = 0; i < 6; ++i) {
        k_dwconv_ln<<<BT_ / 4, 256, 0, stream>>>(h, tmph, tmpl, blk_dw_w + i * H_ * 7,
                                                 blk_dw_b + i * H_, blk_ln_g + i * H_,
                                                 blk_ln_b + i * H_);
        // GEMM1: 128x96 tiles, grid 128m x 16n = 2048 = 4 exact rounds (2/CU)
        k_mgemm96<1, 16><<<2048, 256, 0, stream>>>(
            tmph, tmpl, w1h + (long)i * 589824, w1l + (long)i * 589824,
            blk_b1 + i * H4_, nullptr, nullptr, ht4h, ht4l, H4_, H_);
        // GEMM2: 128x96 tiles, grid 128m x 4n = 512 = exactly 2 blocks/CU
        k_mgemm96<2, 4><<<512, 256, 0, stream>>>(
            ht4h, ht4l, w2h + (long)i * 589824, w2l + (long)i * 589824,
            blk_b2 + i * H_, h, h, nullptr, nullptr, H_, H4_);
    }

    k_outconv_argmin<<<BT_ / 16, 256, 0, stream>>>(h, out_w, out_b, emb, out);
}